// Round 2
// baseline (604.480 us; speedup 1.0000x reference)
//
#include <hip/hip_runtime.h>
#include <hip/hip_bf16.h>

// EMAQuantizer: z[B=32][C=512][H=32][W=32] fp32, embedding[K=1024][C=512] fp32.
// Outputs concat flat in d_out as FP32 (reference outputs fp32 / int32):
//   quantized [32][512][32][32]  (16,777,216 floats)
//   indices   [32][1024]         (32,768 floats; integer values)
#define CDIM 512
#define KDIM 1024
#define HW   1024
#define NPOS 32768
#define P    16      // positions per block

typedef float f4 __attribute__((ext_vector_type(4)));

// ---------------------------------------------------------------------------
// prep: eT[c][k] = e[k][c]; enorm[k] = sum_c e[k][c]^2   (fp32)
// grid: KDIM blocks x 256 threads
// ---------------------------------------------------------------------------
__global__ __launch_bounds__(256) void prep_kernel(const float* __restrict__ e,
                                                   float* __restrict__ eT,
                                                   float* __restrict__ enorm) {
    const int k = blockIdx.x;
    const int t = threadIdx.x;
    const float* row = e + (size_t)k * CDIM;
    float v0 = row[t];
    float v1 = row[t + 256];
    eT[(size_t)t * KDIM + k] = v0;
    eT[(size_t)(t + 256) * KDIM + k] = v1;
    float s = v0 * v0 + v1 * v1;
    #pragma unroll
    for (int off = 32; off > 0; off >>= 1)
        s += __shfl_down(s, off, 64);
    __shared__ float wsum[4];
    if ((t & 63) == 0) wsum[t >> 6] = s;
    __syncthreads();
    if (t == 0) enorm[k] = wsum[0] + wsum[1] + wsum[2] + wsum[3];
}

// ---------------------------------------------------------------------------
// vq: per block: 16 positions, all 1024 codes.
//   d[p][k] = (zsq[p] - 2*dot(z_p,e_k)) + enorm[k]; argmin_k; gather fp32.
// grid: NPOS/P = 2048 blocks x 256 threads
// ---------------------------------------------------------------------------
__global__ __launch_bounds__(256) void vq_kernel(const float* __restrict__ z,
                                                 const float* __restrict__ e,
                                                 const float* __restrict__ eT,
                                                 const float* __restrict__ enorm,
                                                 float* __restrict__ out_q,
                                                 float* __restrict__ out_i) {
    // stride 516 floats: write phase 2-way bank aliasing (free, m136); read
    // phase same-address broadcast (conflict-free). Rows stay 16B-aligned.
    __shared__ float zb[P][CDIM + 4];
    __shared__ float zpart[P][16];
    __shared__ float zsqs[P];
    __shared__ float wval[4][P];
    __shared__ int   widx[4][P];
    __shared__ int   bidx[P];

    const int t   = threadIdx.x;
    const int n0  = blockIdx.x * P;          // first flat position (b*HW + hw)
    const int b   = n0 / HW;
    const int hw0 = n0 % HW;                 // P | HW so block stays in one b

    // ---- stage z tile: zb[p][c] = z[b][c][hw0+p]; partial sum of squares --
    {
        const float* zbase = z + (size_t)b * CDIM * HW + hw0;
        const int p  = t & (P - 1);
        const int c0 = t >> 4;               // 0..15
        float s = 0.0f;
        #pragma unroll
        for (int j = 0; j < CDIM / 16; ++j) {
            const int c = c0 + 16 * j;
            const float v = zbase[(size_t)c * HW + p];
            zb[p][c] = v;
            s += v * v;
        }
        zpart[p][c0] = s;
    }
    __syncthreads();
    if (t < P) {
        float s = 0.0f;
        #pragma unroll
        for (int g = 0; g < 16; ++g) s += zpart[t][g];
        zsqs[t] = s;
    }
    __syncthreads();

    const int wave = t >> 6;                 // 0..3
    const int lane = t & 63;
    const int k4   = wave * 256 + lane * 4;  // 4 consecutive codes per lane

    f4 acc[P];
    #pragma unroll
    for (int p = 0; p < P; ++p) acc[p] = (f4)0.0f;

    // ---- main GEMM-ish loop over channels --------------------------------
    for (int c = 0; c < CDIM; c += 4) {
        const f4 e0 = *(const f4*)(eT + (size_t)(c + 0) * KDIM + k4);
        const f4 e1 = *(const f4*)(eT + (size_t)(c + 1) * KDIM + k4);
        const f4 e2 = *(const f4*)(eT + (size_t)(c + 2) * KDIM + k4);
        const f4 e3 = *(const f4*)(eT + (size_t)(c + 3) * KDIM + k4);
        #pragma unroll
        for (int p = 0; p < P; ++p) {
            const f4 zv = *(const f4*)(&zb[p][c]);
            acc[p] += zv[0] * e0;
            acc[p] += zv[1] * e1;
            acc[p] += zv[2] * e2;
            acc[p] += zv[3] * e3;
        }
    }

    // ---- argmin epilogue --------------------------------------------------
    const f4 en = *(const f4*)(enorm + k4);
    #pragma unroll
    for (int p = 0; p < P; ++p) {
        const float zsq = zsqs[p];
        float bv = (zsq - 2.0f * acc[p][0]) + en[0];
        int   bi = k4;
        float v;
        v = (zsq - 2.0f * acc[p][1]) + en[1]; if (v < bv) { bv = v; bi = k4 + 1; }
        v = (zsq - 2.0f * acc[p][2]) + en[2]; if (v < bv) { bv = v; bi = k4 + 2; }
        v = (zsq - 2.0f * acc[p][3]) + en[3]; if (v < bv) { bv = v; bi = k4 + 3; }
        // wave tree-reduce; ties -> lower index (lower lane = lower k)
        #pragma unroll
        for (int off = 1; off < 64; off <<= 1) {
            const float ov = __shfl_down(bv, off, 64);
            const int   oi = __shfl_down(bi, off, 64);
            if (ov < bv || (ov == bv && oi < bi)) { bv = ov; bi = oi; }
        }
        if (lane == 0) { wval[wave][p] = bv; widx[wave][p] = bi; }
    }
    __syncthreads();

    if (t < P) {
        const int p = t;
        float bv = wval[0][p]; int bi = widx[0][p];
        #pragma unroll
        for (int w = 1; w < 4; ++w) {
            const float ov = wval[w][p]; const int oi = widx[w][p];
            if (ov < bv || (ov == bv && oi < bi)) { bv = ov; bi = oi; }
        }
        bidx[p] = bi;
        out_i[n0 + p] = (float)bi;           // fp32 index value, exact
    }
    __syncthreads();

    // ---- gather + fp32 NCHW write (exact copy of embedding row) ----------
    {
        const int p  = t & (P - 1);
        const int g  = t >> 4;               // 0..15
        const int bi = bidx[p];
        const float* erow = e + (size_t)bi * CDIM;
        float* oq = out_q + (size_t)b * CDIM * HW + hw0 + p;
        #pragma unroll
        for (int j = 0; j < CDIM / 16; ++j) {
            const int c = g + 16 * j;
            oq[(size_t)c * HW] = erow[c];
        }
    }
}

// ---------------------------------------------------------------------------
extern "C" void kernel_launch(void* const* d_in, const int* in_sizes, int n_in,
                              void* d_out, int out_size, void* d_ws, size_t ws_size,
                              hipStream_t stream) {
    const float* z = (const float*)d_in[0];
    const float* e = (const float*)d_in[1];

    float* out_q = (float*)d_out;
    float* out_i = out_q + (out_size - NPOS);    // indices after quantized

    float* eT    = (float*)d_ws;                 // [CDIM][KDIM] = 2 MB
    float* enorm = eT + (size_t)CDIM * KDIM;     // [KDIM]

    prep_kernel<<<KDIM, 256, 0, stream>>>(e, eT, enorm);
    vq_kernel<<<NPOS / P, 256, 0, stream>>>(z, e, eT, enorm, out_q, out_i);
}

// Round 3
// 231.227 us; speedup vs baseline: 2.6142x; 2.6142x over previous
//
#include <hip/hip_runtime.h>
#include <hip/hip_bf16.h>

// EMAQuantizer: z[32][512][32][32] fp32, embedding[1024][512] fp32.
// d_out fp32 concat: quantized [32][512][32][32] then indices [32][1024].
#define CDIM 512
#define KDIM 1024
#define HW   1024
#define NPOS 32768
#define BM   128            // positions per block
#define BN   128            // codes per block
#define BK   64             // channels per K-step
#define NKS  (CDIM / BK)    // 8 K-steps
#define NNB  (KDIM / BN)    // 8 code-blocks
#define TILE_USHORT (8 * 128 * 8)   // one 16KB tile image in ushorts

typedef float  f32x16 __attribute__((ext_vector_type(16)));
typedef float  f4     __attribute__((ext_vector_type(4)));
typedef short  bf16x8 __attribute__((ext_vector_type(8)));
typedef unsigned int u32x4 __attribute__((ext_vector_type(4)));

static __device__ __forceinline__ unsigned short f2bf(float f) {
    __hip_bfloat16 h = __float2bfloat16(f);           // RNE
    union { __hip_bfloat16 h; unsigned short u; } cv; cv.h = h; return cv.u;
}
static __device__ __forceinline__ float bf2f(unsigned short u) {
    union { unsigned short u; __hip_bfloat16 h; } cv; cv.u = u; return __bfloat162float(cv.h);
}

// ---------------------------------------------------------------------------
// prep_e: embedding -> Bt_hi/Bt_lo in GEMM tile-image layout + enorm.
// Tile image for (nb, ks): [slot 0..7][row 0..127][8 bf16] (16 KB), so the
// GEMM can stage B with contiguous 16B loads and linear ds_writes.
// grid: KDIM blocks x 64 threads (1 wave).
// ---------------------------------------------------------------------------
__global__ __launch_bounds__(64) void prep_e(const float* __restrict__ e,
                                             unsigned short* __restrict__ Bt_hi,
                                             unsigned short* __restrict__ Bt_lo,
                                             float* __restrict__ enorm) {
    const int k  = blockIdx.x;
    const int t  = threadIdx.x;
    const int nb = k >> 7, row = k & 127;
    const int ks = t >> 3, slot = t & 7;

    const f4* src = (const f4*)(e + (size_t)k * CDIM + ks * 64 + slot * 8);
    const f4 a = src[0], b = src[1];
    float v[8] = {a.x, a.y, a.z, a.w, b.x, b.y, b.z, b.w};

    unsigned int hw_[4], lw_[4];
    float ss = 0.0f;
    #pragma unroll
    for (int d = 0; d < 4; ++d) {
        const float v0 = v[2 * d], v1 = v[2 * d + 1];
        const unsigned short h0 = f2bf(v0), h1 = f2bf(v1);
        hw_[d] = (unsigned int)h0 | ((unsigned int)h1 << 16);
        lw_[d] = (unsigned int)f2bf(v0 - bf2f(h0)) |
                 ((unsigned int)f2bf(v1 - bf2f(h1)) << 16);
        ss += v0 * v0 + v1 * v1;
    }
    const size_t off = ((((size_t)nb * 8 + ks) * 8 + slot) * 128 + row) * 8;
    *(u32x4*)(Bt_hi + off) = u32x4{hw_[0], hw_[1], hw_[2], hw_[3]};
    *(u32x4*)(Bt_lo + off) = u32x4{lw_[0], lw_[1], lw_[2], lw_[3]};

    #pragma unroll
    for (int o = 32; o > 0; o >>= 1) ss += __shfl_down(ss, o, 64);
    if (t == 0) enorm[k] = ss;
}

// ---------------------------------------------------------------------------
// vq_gemm: per block 128 positions x 128 codes, 3-pass split-bf16 MFMA.
// LDS tiles slot-major [octet][row][8 bf16] -> conflict-free frag reads.
// Swapped operands: codes are MFMA rows, positions are cols, so the argmin
// over codes is lane-local (16 regs x 2 frags) + one xor-32 shuffle.
// Partial (val, idx) per (pos, code-block) -> part[pos*8 + nb].
// grid: (NPOS/BM)*(KDIM/BN) = 2048 blocks x 256 threads.
// ---------------------------------------------------------------------------
__global__ __launch_bounds__(256) void vq_gemm(const float* __restrict__ z,
                                               const unsigned short* __restrict__ Bt_hi,
                                               const unsigned short* __restrict__ Bt_lo,
                                               const float* __restrict__ enorm,
                                               float2* __restrict__ part) {
    __shared__ unsigned short Ah[8][128][8], Al[8][128][8];
    __shared__ unsigned short Bh[8][128][8], Bl[8][128][8];
    __shared__ float lval[2][128];
    __shared__ int   lidx[2][128];

    // XCD-chunked order: xcd x gets m-panels [x*32, x*32+32), nb fastest, so
    // the 8 code-blocks sharing one z-panel hit the same XCD L2.
    const int bid = blockIdx.x;
    const int x = bid & 7, jj = bid >> 3;
    const int m  = x * 32 + (jj >> 3);
    const int nb = jj & 7;

    const int n0  = m * BM;
    const int b   = n0 >> 10;
    const int hw0 = n0 & 1023;

    const int t   = threadIdx.x;
    const int wid = t >> 6, l = t & 63;
    const int wr  = wid >> 1, wc = wid & 1;   // code-half, pos-half

    f32x16 acc[2][2];
    #pragma unroll
    for (int i = 0; i < 2; ++i)
        #pragma unroll
        for (int j = 0; j < 2; ++j) acc[i][j] = (f32x16)0.0f;

    const float* zbase = z + (size_t)b * CDIM * HW + hw0;
    const int sp = t & 127;      // staging pos
    const int sh = t >> 7;       // staging c-half (32 channels)

    for (int ks = 0; ks < NKS; ++ks) {
        // ---- issue A loads (32 scalars: all c for my pos) ----------------
        float v[32];
        const float* zc = zbase + (size_t)(ks * 64 + sh * 32) * HW + sp;
        #pragma unroll
        for (int i = 0; i < 32; ++i) v[i] = zc[(size_t)i * HW];
        // ---- issue B loads (tile image is LDS-linear) --------------------
        u32x4 bhv[4], blv[4];
        const u32x4* bsh = (const u32x4*)(Bt_hi + ((size_t)nb * 8 + ks) * TILE_USHORT);
        const u32x4* bsl = (const u32x4*)(Bt_lo + ((size_t)nb * 8 + ks) * TILE_USHORT);
        #pragma unroll
        for (int q = 0; q < 4; ++q) { bhv[q] = bsh[q * 256 + t]; blv[q] = bsl[q * 256 + t]; }

        __syncthreads();   // previous compute done; safe to overwrite LDS

        // ---- convert + write A (slot-major) ------------------------------
        #pragma unroll
        for (int o = 0; o < 4; ++o) {
            unsigned int hw_[4], lw_[4];
            #pragma unroll
            for (int d = 0; d < 4; ++d) {
                const float a0 = v[o * 8 + 2 * d], a1 = v[o * 8 + 2 * d + 1];
                const unsigned short h0 = f2bf(a0), h1 = f2bf(a1);
                hw_[d] = (unsigned int)h0 | ((unsigned int)h1 << 16);
                lw_[d] = (unsigned int)f2bf(a0 - bf2f(h0)) |
                         ((unsigned int)f2bf(a1 - bf2f(h1)) << 16);
            }
            *(u32x4*)&Ah[sh * 4 + o][sp][0] = u32x4{hw_[0], hw_[1], hw_[2], hw_[3]};
            *(u32x4*)&Al[sh * 4 + o][sp][0] = u32x4{lw_[0], lw_[1], lw_[2], lw_[3]};
        }
        // ---- write B (linear) --------------------------------------------
        unsigned short* bhp = &Bh[0][0][0];
        unsigned short* blp = &Bl[0][0][0];
        #pragma unroll
        for (int q = 0; q < 4; ++q) {
            *(u32x4*)(bhp + (size_t)(q * 256 + t) * 8) = bhv[q];
            *(u32x4*)(blp + (size_t)(q * 256 + t) * 8) = blv[q];
        }
        __syncthreads();

        // ---- compute: 4 k-subs x (2x2 frags x 3 passes) ------------------
        #pragma unroll
        for (int ksub = 0; ksub < 4; ++ksub) {
            const int so = 2 * ksub + (l >> 5);
            const int cr = wr * 64 + (l & 31);
            const int pr = wc * 64 + (l & 31);
            const bf16x8 ch0 = *(const bf16x8*)&Bh[so][cr][0];
            const bf16x8 ch1 = *(const bf16x8*)&Bh[so][cr + 32][0];
            const bf16x8 cl0 = *(const bf16x8*)&Bl[so][cr][0];
            const bf16x8 cl1 = *(const bf16x8*)&Bl[so][cr + 32][0];
            const bf16x8 ph0 = *(const bf16x8*)&Ah[so][pr][0];
            const bf16x8 ph1 = *(const bf16x8*)&Ah[so][pr + 32][0];
            const bf16x8 pl0 = *(const bf16x8*)&Al[so][pr][0];
            const bf16x8 pl1 = *(const bf16x8*)&Al[so][pr + 32][0];
            // pass 1: hi*hi
            acc[0][0] = __builtin_amdgcn_mfma_f32_32x32x16_bf16(ch0, ph0, acc[0][0], 0, 0, 0);
            acc[0][1] = __builtin_amdgcn_mfma_f32_32x32x16_bf16(ch0, ph1, acc[0][1], 0, 0, 0);
            acc[1][0] = __builtin_amdgcn_mfma_f32_32x32x16_bf16(ch1, ph0, acc[1][0], 0, 0, 0);
            acc[1][1] = __builtin_amdgcn_mfma_f32_32x32x16_bf16(ch1, ph1, acc[1][1], 0, 0, 0);
            // pass 2: hi*lo
            acc[0][0] = __builtin_amdgcn_mfma_f32_32x32x16_bf16(ch0, pl0, acc[0][0], 0, 0, 0);
            acc[0][1] = __builtin_amdgcn_mfma_f32_32x32x16_bf16(ch0, pl1, acc[0][1], 0, 0, 0);
            acc[1][0] = __builtin_amdgcn_mfma_f32_32x32x16_bf16(ch1, pl0, acc[1][0], 0, 0, 0);
            acc[1][1] = __builtin_amdgcn_mfma_f32_32x32x16_bf16(ch1, pl1, acc[1][1], 0, 0, 0);
            // pass 3: lo*hi
            acc[0][0] = __builtin_amdgcn_mfma_f32_32x32x16_bf16(cl0, ph0, acc[0][0], 0, 0, 0);
            acc[0][1] = __builtin_amdgcn_mfma_f32_32x32x16_bf16(cl0, ph1, acc[0][1], 0, 0, 0);
            acc[1][0] = __builtin_amdgcn_mfma_f32_32x32x16_bf16(cl1, ph0, acc[1][0], 0, 0, 0);
            acc[1][1] = __builtin_amdgcn_mfma_f32_32x32x16_bf16(cl1, ph1, acc[1][1], 0, 0, 0);
        }
    }

    // ---- argmin epilogue: dist = enorm[code] - 2*dot ---------------------
    // C/D layout (m74/m101): col = lane&31 (pos), row = (reg&3)+8*(reg>>2)+4*(lane>>5).
    const float* en = enorm + nb * 128 + wr * 64;
    #pragma unroll
    for (int pj = 0; pj < 2; ++pj) {
        float bv = 1e30f; int bi = 1 << 20;
        #pragma unroll
        for (int ci = 0; ci < 2; ++ci) {
            #pragma unroll
            for (int r = 0; r < 16; ++r) {
                const int code = ci * 32 + (r & 3) + 8 * (r >> 2) + 4 * (l >> 5);
                const float val = en[code] - 2.0f * acc[ci][pj][r];
                if (val < bv || (val == bv && code < bi)) { bv = val; bi = code; }
            }
        }
        const float ov = __shfl_xor(bv, 32, 64);
        const int   oi = __shfl_xor(bi, 32, 64);
        if (ov < bv || (ov == bv && oi < bi)) { bv = ov; bi = oi; }
        if (l < 32) { lval[wr][wc * 64 + pj * 32 + l] = bv; lidx[wr][wc * 64 + pj * 32 + l] = bi; }
    }
    __syncthreads();

    if (t < 128) {
        const float v0 = lval[0][t]; const int i0 = lidx[0][t];
        const float v1 = lval[1][t]; const int i1 = lidx[1][t] + 64;
        float bv = v0; int bi = i0;
        if (v1 < bv || (v1 == bv && i1 < bi)) { bv = v1; bi = i1; }
        part[(size_t)(n0 + t) * 8 + nb] = make_float2(bv, (float)(nb * 128 + bi));
    }
}

// ---------------------------------------------------------------------------
// vq_reduce: combine 8 partials per position, write indices (fp32 ints) and
// gather embedding rows -> fp32 NCHW quantized output.
// grid: NPOS/128 = 256 blocks x 256 threads.
// ---------------------------------------------------------------------------
__global__ __launch_bounds__(256) void vq_reduce(const float2* __restrict__ part,
                                                 const float* __restrict__ e,
                                                 float* __restrict__ out_q,
                                                 float* __restrict__ out_i) {
    __shared__ int bidx[128];
    const int t  = threadIdx.x;
    const int p0 = blockIdx.x * 128;

    if (t < 128) {
        const int n = p0 + t;
        const float2* pr = part + (size_t)n * 8;
        float bv = pr[0].x; int bi = (int)pr[0].y;
        #pragma unroll
        for (int nb = 1; nb < 8; ++nb) {
            const float2 c = pr[nb];
            const int ci = (int)c.y;
            if (c.x < bv || (c.x == bv && ci < bi)) { bv = c.x; bi = ci; }
        }
        bidx[t] = bi;
        out_i[n] = (float)bi;
    }
    __syncthreads();

    const int p = t & 127, h = t >> 7;
    const int n = p0 + p;
    const int b = n >> 10, hwp = n & 1023;
    const f4* e4 = (const f4*)(e + (size_t)bidx[p] * CDIM);
    float* oq = out_q + (size_t)b * CDIM * HW + hwp;
    #pragma unroll 4
    for (int j = 0; j < 64; ++j) {
        const f4 vv = e4[h * 64 + j];
        const int c = h * 256 + j * 4;
        oq[(size_t)(c + 0) * HW] = vv.x;
        oq[(size_t)(c + 1) * HW] = vv.y;
        oq[(size_t)(c + 2) * HW] = vv.z;
        oq[(size_t)(c + 3) * HW] = vv.w;
    }
}

// ---------------------------------------------------------------------------
extern "C" void kernel_launch(void* const* d_in, const int* in_sizes, int n_in,
                              void* d_out, int out_size, void* d_ws, size_t ws_size,
                              hipStream_t stream) {
    const float* z = (const float*)d_in[0];
    const float* e = (const float*)d_in[1];

    float* out_q = (float*)d_out;
    float* out_i = out_q + (out_size - NPOS);

    // ws layout (≈4.2 MB): Bt_hi 1MB | Bt_lo 1MB | enorm 4KB | part 2MB
    unsigned short* Bt_hi = (unsigned short*)d_ws;
    unsigned short* Bt_lo = Bt_hi + (size_t)KDIM * CDIM;
    float*  enorm = (float*)(Bt_lo + (size_t)KDIM * CDIM);
    float2* part  = (float2*)((char*)d_ws + 2 * 1048576 + 4096);

    prep_e<<<KDIM, 64, 0, stream>>>(e, Bt_hi, Bt_lo, enorm);
    vq_gemm<<<(NPOS / BM) * NNB, 256, 0, stream>>>(z, Bt_hi, Bt_lo, enorm, part);
    vq_reduce<<<NPOS / 128, 256, 0, stream>>>(part, e, out_q, out_i);
}